// Round 12
// baseline (513.684 us; speedup 1.0000x reference)
//
#include <hip/hip_runtime.h>
#include <stdint.h>

// bf16 flash-attention forward, causal, B=2 H=16 T=4096 D=128, fp32 in/out.
// S^T = K*Q^T (q on lane&31 for softmax), O^T = V^T*P^T (alpha per-lane).
// R17: intra-block kv-split for 16 waves/CU with UNIFORM 33-iter blocks.
//
// Measured law (R8 306us > R15 351us > R7 398us): uniform per-BLOCK duration
// + constant residency wins; per-CU work balance without backfill loses
// (light blocks drain, heavy runs alone). R15: Occ 18.8 vs predicted 38.
//
// R17: 512 blocks x 512 threads (8 waves). Group g = waves 4g..4g+3 takes
// kv tiles 2i+g of the SAME q-tile (private staging buffer each); online
// softmax per group; LDS combine at q-tile end (flash merge, aB=0-safe for
// all-masked group-1 waves). Blocks pair qt={31-pr, pr} sequentially ->
// every block exactly (32-pr)+(pr+1) = 33 iterations. 2 blocks/CU = 16
// waves/CU sustained (VGPR 116-128 -> 4 waves/SIMD; LDS 2x71680=143K<=160K).
// launch_bounds(512,2): budget 256 VGPR — no R11-style spill forcing.
//
// Body per group = R7/R8 verified: P-in-register via sigma-permuted Vt,
// defer-max, setprio, register prefetch double-buffer.

typedef __bf16 bf16x8 __attribute__((ext_vector_type(8)));
typedef float f32x16 __attribute__((ext_vector_type(16)));
typedef unsigned short u16x8 __attribute__((ext_vector_type(8)));
typedef unsigned int u32x2 __attribute__((ext_vector_type(2)));

#define T_SEQ 4096
#define D_HEAD 128
#define BQ 128          // q rows per q-tile (4 waves x 32)
#define NQT (T_SEQ / BQ) // 32 q-tiles
#define BK 64           // kv rows per tile
#define KSTR 136        // K_lds row stride in shorts (128 + 8 pad)
#define VSTR 72         // Vt_lds row stride in shorts (64 + 8 pad)

// pack two f32 -> bf16x2 (round-half-up: +0x8000, take hi16). 3 VALU / 2 elem.
__device__ __forceinline__ unsigned int pack_bf2(float a, float b) {
    unsigned int ua = __builtin_bit_cast(unsigned int, a) + 0x8000u;
    unsigned int ub = __builtin_bit_cast(unsigned int, b) + 0x8000u;
    return __builtin_amdgcn_perm(ub, ua, 0x07060302);  // [ub.hi16 | ua.hi16]
}

__global__ __launch_bounds__(512, 2) void fa_fwd(
    const float* __restrict__ Qg, const float* __restrict__ Kg,
    const float* __restrict__ Vg, float* __restrict__ Og)
{
    __shared__ unsigned short K_lds[2][BK * KSTR];      // per-group K[kv][d]   2x17408 B
    __shared__ unsigned short Vt_lds[2][D_HEAD * VSTR]; // per-group V^T        2x18432 B

    const int tid  = (int)threadIdx.x;    // 0..511
    const int grp  = tid >> 8;            // 0: even kv tiles, 1: odd
    const int gtid = tid & 255;
    const int w    = gtid >> 6;           // wave within group 0..3
    const int lane = tid & 63;
    const int r    = lane & 31;           // n-index within MFMA tiles
    const int h    = lane >> 5;           // half-wave

    const int bid = (int)blockIdx.x;      // 0..511
    const int pr  = bid & 15;             // pair id 0..15
    const int bh  = bid >> 4;             // 0..31

    const float* Qb = Qg + (size_t)bh * T_SEQ * D_HEAD;
    const float* Kb = Kg + (size_t)bh * T_SEQ * D_HEAD;
    const float* Vb = Vg + (size_t)bh * T_SEQ * D_HEAD;
    float*       Ob = Og + (size_t)bh * T_SEQ * D_HEAD;

    unsigned short* Kl = &K_lds[grp][0];
    unsigned short* Vl = &Vt_lds[grp][0];
    // combine overlay (reuses staging LDS after kv loop; stride 33 floats ->
    // consecutive lanes hit consecutive banks, conflict-free scalar traffic)
    float* cb  = (float*)&K_lds[0][0];    // 256*33*4 = 33792 B <= 34816 B
    float* cml = (float*)&Vt_lds[0][0];   // 256*2*4  =  2048 B <= 36864 B

    // staging geometry (group-local)
    const int krow = gtid >> 5;           // 0..7
    const int kd0  = (gtid & 31) * 4;
    const int vd   = gtid & 127;
    const int vhh  = gtid >> 7;           // 0,1

    const float qscale = 0.08838834764831845f * 1.4426950408889634f;

    for (int phase = 0; phase < 2; ++phase) {
        const int qt = (phase == 0) ? (NQT - 1 - pr) : pr;  // heavy first
        const int q0 = qt * BQ;
        const int qw      = q0 + 32 * w;
        const int q_lane  = qw + r;
        const int qw_last = qw + 31;

        // ---- Q fragments (B-operand), pre-scaled by 1/sqrt(D)*log2(e)
        bf16x8 qf[8];
#pragma unroll
        for (int c = 0; c < 8; ++c) {
            const float* src = Qb + (size_t)q_lane * D_HEAD + c * 16 + h * 8;
            float4 f0 = *(const float4*)(src);
            float4 f1 = *(const float4*)(src + 4);
            unsigned int u0 = pack_bf2(f0.x * qscale, f0.y * qscale);
            unsigned int u1 = pack_bf2(f0.z * qscale, f0.w * qscale);
            unsigned int u2 = pack_bf2(f1.x * qscale, f1.y * qscale);
            unsigned int u3 = pack_bf2(f1.z * qscale, f1.w * qscale);
            u16x8 u = { (unsigned short)u0, (unsigned short)(u0 >> 16),
                        (unsigned short)u1, (unsigned short)(u1 >> 16),
                        (unsigned short)u2, (unsigned short)(u2 >> 16),
                        (unsigned short)u3, (unsigned short)(u3 >> 16) };
            qf[c] = __builtin_bit_cast(bf16x8, u);
        }

        f32x16 o[4];
#pragma unroll
        for (int mt = 0; mt < 4; ++mt) o[mt] = (f32x16)0.0f;
        float m_run = -1e30f, l_run = 0.0f;

        // ---- prefetch registers; this group's first tile is tile index grp
        float4 kpre[8];
        float  vpre[8][4];
        {
            const int tb = grp * BK;
#pragma unroll
            for (int p = 0; p < 8; ++p)
                kpre[p] = *(const float4*)(Kb + (size_t)(tb + p * 8 + krow) * D_HEAD + kd0);
#pragma unroll
            for (int p = 0; p < 8; ++p) {
                const int kv0 = tb + p * 8 + vhh * 4;
                const float* vs = Vb + (size_t)kv0 * D_HEAD + vd;
                vpre[p][0] = vs[0];
                vpre[p][1] = vs[D_HEAD];
                vpre[p][2] = vs[2 * D_HEAD];
                vpre[p][3] = vs[3 * D_HEAD];
            }
        }

        const int niter = qt + 1;   // per group; total tiles = 2qt+2 across groups
        for (int i = 0; i < niter; ++i) {
            const int kbase = (2 * i + grp) * BK;
            __syncthreads();   // prev compute done with LDS; drains prefetch vmcnt

            // ---- write prefetched tile into this group's LDS (pack to bf16)
#pragma unroll
            for (int p = 0; p < 8; ++p) {
                u32x2 u;
                u[0] = pack_bf2(kpre[p].x, kpre[p].y);
                u[1] = pack_bf2(kpre[p].z, kpre[p].w);
                *(u32x2*)&Kl[(p * 8 + krow) * KSTR + kd0] = u;
            }
            // V columns permuted within tile: col = sigma(kv-offset), swap bits 2,3
#pragma unroll
            for (int p = 0; p < 8; ++p) {
                u32x2 u;
                u[0] = pack_bf2(vpre[p][0], vpre[p][1]);
                u[1] = pack_bf2(vpre[p][2], vpre[p][3]);
                const int col = (p >> 1) * 16 + vhh * 8 + (p & 1) * 4;
                *(u32x2*)&Vl[vd * VSTR + col] = u;
            }
            __syncthreads();

            // ---- issue next tile's global loads (this group's tile 2(i+1)+grp)
            if (i + 1 < niter) {
                const int nb = (2 * (i + 1) + grp) * BK;
#pragma unroll
                for (int p = 0; p < 8; ++p)
                    kpre[p] = *(const float4*)(Kb + (size_t)(nb + p * 8 + krow) * D_HEAD + kd0);
#pragma unroll
                for (int p = 0; p < 8; ++p) {
                    const int kv0 = nb + p * 8 + vhh * 4;
                    const float* vs = Vb + (size_t)kv0 * D_HEAD + vd;
                    vpre[p][0] = vs[0];
                    vpre[p][1] = vs[D_HEAD];
                    vpre[p][2] = vs[2 * D_HEAD];
                    vpre[p][3] = vs[3 * D_HEAD];
                }
            }

            if (kbase > qw_last) continue;   // wave-uniform; barriers stay aligned

            // ---- S^T = K * Q^T : two 32-kv m-tiles
            f32x16 s[2];
            s[0] = (f32x16)0.0f; s[1] = (f32x16)0.0f;
            __builtin_amdgcn_s_setprio(1);
#pragma unroll
            for (int t2 = 0; t2 < 2; ++t2) {
#pragma unroll
                for (int c = 0; c < 8; ++c) {
                    u16x8 raw = *(const u16x8*)&Kl[(t2 * 32 + r) * KSTR + c * 16 + h * 8];
                    bf16x8 a = __builtin_bit_cast(bf16x8, raw);
                    s[t2] = __builtin_amdgcn_mfma_f32_32x32x16_bf16(a, qf[c], s[t2], 0, 0, 0);
                }
            }
            __builtin_amdgcn_s_setprio(0);

            // ---- causal mask (vs wave's FIRST q)
            if (kbase + BK - 1 > qw) {
#pragma unroll
                for (int t2 = 0; t2 < 2; ++t2)
#pragma unroll
                    for (int g2 = 0; g2 < 16; ++g2) {
                        int kv = kbase + t2 * 32 + (g2 & 3) + 8 * (g2 >> 2) + 4 * h;
                        if (kv > q_lane) s[t2][g2] = -1e30f;
                    }
            }

            // ---- online softmax (per q = lane&31; combine two half-waves)
            float mloc = -1e30f;
#pragma unroll
            for (int t2 = 0; t2 < 2; ++t2)
#pragma unroll
                for (int g2 = 0; g2 < 16; ++g2) mloc = fmaxf(mloc, s[t2][g2]);
            mloc = fmaxf(mloc, __shfl_xor(mloc, 32, 64));

            // T13 defer-max: only rescale when some row's max grew by > 8 (log2).
            if (!__all(mloc - m_run <= 8.0f)) {
                const float m_new = fmaxf(m_run, mloc);
                const float alpha = __builtin_amdgcn_exp2f(m_run - m_new);
                l_run *= alpha;
#pragma unroll
                for (int mt = 0; mt < 4; ++mt)
#pragma unroll
                    for (int g2 = 0; g2 < 16; ++g2) o[mt][g2] *= alpha;
                m_run = m_new;
            }

            float rsum = 0.0f;
#pragma unroll
            for (int t2 = 0; t2 < 2; ++t2)
#pragma unroll
                for (int g2 = 0; g2 < 16; ++g2) {
                    float p = __builtin_amdgcn_exp2f(s[t2][g2] - m_run);
                    s[t2][g2] = p;
                    rsum += p;
                }
            rsum += __shfl_xor(rsum, 32, 64);
            l_run += rsum;

            // ---- P^T B-fragments directly from registers (sigma pairing)
            bf16x8 pf[4];
#pragma unroll
            for (int c = 0; c < 4; ++c) {
                const int tt = c >> 1;
                const int g0 = (c & 1) * 8;
                unsigned int u0 = pack_bf2(s[tt][g0 + 0], s[tt][g0 + 1]);
                unsigned int u1 = pack_bf2(s[tt][g0 + 2], s[tt][g0 + 3]);
                unsigned int u2 = pack_bf2(s[tt][g0 + 4], s[tt][g0 + 5]);
                unsigned int u3 = pack_bf2(s[tt][g0 + 6], s[tt][g0 + 7]);
                u16x8 u = { (unsigned short)u0, (unsigned short)(u0 >> 16),
                            (unsigned short)u1, (unsigned short)(u1 >> 16),
                            (unsigned short)u2, (unsigned short)(u2 >> 16),
                            (unsigned short)u3, (unsigned short)(u3 >> 16) };
                pf[c] = __builtin_bit_cast(bf16x8, u);
            }

            // ---- O^T += V^T * P^T
            __builtin_amdgcn_s_setprio(1);
#pragma unroll
            for (int mt = 0; mt < 4; ++mt) {
#pragma unroll
                for (int c = 0; c < 4; ++c) {
                    u16x8 raw = *(const u16x8*)&Vl[(mt * 32 + r) * VSTR + c * 16 + h * 8];
                    bf16x8 a = __builtin_bit_cast(bf16x8, raw);
                    o[mt] = __builtin_amdgcn_mfma_f32_32x32x16_bf16(a, pf[c], o[mt], 0, 0, 0);
                }
            }
            __builtin_amdgcn_s_setprio(0);
        }

        // ---- cross-group combine (flash merge), two 32KB passes through cb.
        // Group 1 all-masked waves carry m=-1e30, l=0 -> aB=exp2(-1e30)=0:
        // degenerates safely to group 0's result. Group 0 always has >=1 tile.
        __syncthreads();                       // both groups' kv loops done
        if (grp == 1) {
            cml[gtid * 2 + 0] = m_run;
            cml[gtid * 2 + 1] = l_run;
#pragma unroll
            for (int mt = 0; mt < 2; ++mt)
#pragma unroll
                for (int g2 = 0; g2 < 16; ++g2)
                    cb[gtid * 33 + mt * 16 + g2] = o[mt][g2];
        }
        __syncthreads();
        float aA = 1.0f, aB = 0.0f, linv = 0.0f;
        if (grp == 0) {
            const float mB = cml[gtid * 2 + 0];
            const float lB = cml[gtid * 2 + 1];
            const float m  = fmaxf(m_run, mB);
            aA = __builtin_amdgcn_exp2f(m_run - m);
            aB = __builtin_amdgcn_exp2f(mB - m);
            linv = 1.0f / (l_run * aA + lB * aB);
#pragma unroll
            for (int mt = 0; mt < 2; ++mt)
#pragma unroll
                for (int g4 = 0; g4 < 4; ++g4) {
                    const int b = gtid * 33 + mt * 16 + g4 * 4;
                    float4 vv;
                    vv.x = (o[mt][g4 * 4 + 0] * aA + cb[b + 0] * aB) * linv;
                    vv.y = (o[mt][g4 * 4 + 1] * aA + cb[b + 1] * aB) * linv;
                    vv.z = (o[mt][g4 * 4 + 2] * aA + cb[b + 2] * aB) * linv;
                    vv.w = (o[mt][g4 * 4 + 3] * aA + cb[b + 3] * aB) * linv;
                    const int dd = mt * 32 + g4 * 8 + h * 4;
                    *(float4*)(Ob + (size_t)q_lane * D_HEAD + dd) = vv;
                }
        }
        __syncthreads();
        if (grp == 1) {
#pragma unroll
            for (int mt = 2; mt < 4; ++mt)
#pragma unroll
                for (int g2 = 0; g2 < 16; ++g2)
                    cb[gtid * 33 + (mt - 2) * 16 + g2] = o[mt][g2];
        }
        __syncthreads();
        if (grp == 0) {
#pragma unroll
            for (int mt = 2; mt < 4; ++mt)
#pragma unroll
                for (int g4 = 0; g4 < 4; ++g4) {
                    const int b = gtid * 33 + (mt - 2) * 16 + g4 * 4;
                    float4 vv;
                    vv.x = (o[mt][g4 * 4 + 0] * aA + cb[b + 0] * aB) * linv;
                    vv.y = (o[mt][g4 * 4 + 1] * aA + cb[b + 1] * aB) * linv;
                    vv.z = (o[mt][g4 * 4 + 2] * aA + cb[b + 2] * aB) * linv;
                    vv.w = (o[mt][g4 * 4 + 3] * aA + cb[b + 3] * aB) * linv;
                    const int dd = mt * 32 + g4 * 8 + h * 4;
                    *(float4*)(Ob + (size_t)q_lane * D_HEAD + dd) = vv;
                }
        }
        // next phase's loop-top __syncthreads() protects LDS reuse
    }
}

extern "C" void kernel_launch(void* const* d_in, const int* in_sizes, int n_in,
                              void* d_out, int out_size, void* d_ws, size_t ws_size,
                              hipStream_t stream) {
    const float* Q = (const float*)d_in[0];
    const float* K = (const float*)d_in[1];
    const float* V = (const float*)d_in[2];
    float* O = (float*)d_out;
    dim3 grid((NQT / 2) * 32, 1, 1);   // 16 pairs x 32 bh = 512 blocks
    fa_fwd<<<grid, 512, 0, stream>>>(Q, K, V, O);
}